// Round 3
// baseline (2396.056 us; speedup 1.0000x reference)
//
#include <hip/hip_runtime.h>

#define H 128
#define EIN 304
#define NIN 272
#define BM 64
#define BK 16
#define NT 256
#define LN_EPS 1e-5f

__device__ __forceinline__ float silu_f(float x) {
    return x / (1.0f + __expf(-x));
}

__device__ __forceinline__ void atomic_add_f32(float* p, float v) {
    unsafeAtomicAdd(p, v);
}

// ---------------------------------------------------------------------------
// Edge kernel: per 64-edge tile, gather 304-dim edge features, run
// MLP1(304->128)+silu, MLP2(128->128)+silu fully in LDS/registers, then
// atomically scatter-add the 128-dim message into agg[dst].
// ---------------------------------------------------------------------------
__global__ void __launch_bounds__(NT)
edge_mlp_scatter(const float* __restrict__ h,
                 const int* __restrict__ esrc,
                 const int* __restrict__ edst,
                 const int* __restrict__ erel,
                 const int* __restrict__ ncol,
                 const int* __restrict__ nrole,
                 const float* __restrict__ rel_emb,
                 const float* __restrict__ role_emb,
                 const float* __restrict__ col_emb,
                 const float* __restrict__ eW1,
                 const float* __restrict__ eb1,
                 const float* __restrict__ eW2,
                 const float* __restrict__ eb2,
                 float* __restrict__ agg,
                 int E)
{
    __shared__ float sA[BK][BM + 4];     // A-tile, [k][edge]
    __shared__ float sB[BK][H + 4];      // W-tile, [k][col]
    __shared__ float sY[BM][H + 4];      // MLP1 output, [edge][feat]
    __shared__ int sSrc[BM], sDst[BM], sRel[BM], sRS[BM], sRD[BM], sCS[BM], sCD[BM];
    __shared__ float sRelE[128], sRoleE[48], sColE[24];

    const int tid = threadIdx.x;
    const int tx = tid & 15;          // col group
    const int ty = tid >> 4;          // row group
    const int r0 = ty * 4;            // rows r0..r0+3
    const int c0 = tx * 8;            // cols c0..c0+7
    const int e0 = blockIdx.x * BM;

    if (tid < 128) sRelE[tid] = rel_emb[tid];
    if (tid < 48)  sRoleE[tid] = role_emb[tid];
    if (tid < 24)  sColE[tid] = col_emb[tid];
    if (tid < BM) {
        int e = e0 + tid;
        int s = 0, d = 0, r = 0;
        if (e < E) { s = esrc[e]; d = edst[e]; r = erel[e]; }
        sSrc[tid] = s; sDst[tid] = d; sRel[tid] = r;
        sRS[tid] = nrole[s]; sRD[tid] = nrole[d];
        sCS[tid] = ncol[s];  sCD[tid] = ncol[d];
    }

    float bias1[8], bias2[8];
    #pragma unroll
    for (int j = 0; j < 8; j++) { bias1[j] = eb1[c0 + j]; bias2[j] = eb2[c0 + j]; }

    float acc[4][8];
    #pragma unroll
    for (int i = 0; i < 4; i++)
        #pragma unroll
        for (int j = 0; j < 8; j++) acc[i][j] = 0.0f;

    __syncthreads();

    // ---- MLP1: [64 x 304] @ [304 x 128] ----
    for (int kk = 0; kk < EIN / BK; kk++) {
        const int k0 = kk * BK;
        // stage gathered A-tile (transposed [k][e]); lane k = tx, edge = ty+16*it
        {
            const int k = k0 + tx;
            #pragma unroll
            for (int it = 0; it < 4; it++) {
                const int e = ty + it * 16;
                float v;
                if (k < 128) {
                    v = h[sSrc[e] * H + k];
                } else if (k < 256) {
                    v = h[sDst[e] * H + (k - 128)];
                } else {
                    const int j = k - 256;
                    if (j < 16)      v = sRelE[sRel[e] * 16 + j];
                    else if (j < 24) v = sRoleE[sRS[e] * 8 + (j - 16)];
                    else if (j < 32) v = sRoleE[sRD[e] * 8 + (j - 24)];
                    else if (j < 40) v = sColE[sCS[e] * 8 + (j - 32)];
                    else             v = sColE[sCD[e] * 8 + (j - 40)];
                }
                sA[tx][e] = v;
            }
        }
        // stage B-tile (row ty of this K-slice, 8 cols at c0)
        {
            const float4* g = (const float4*)&eW1[(k0 + ty) * H + c0];
            *(float4*)&sB[ty][c0]     = g[0];
            *(float4*)&sB[ty][c0 + 4] = g[1];
        }
        __syncthreads();
        #pragma unroll
        for (int k = 0; k < BK; k++) {
            const float4 a  = *(const float4*)&sA[k][r0];
            const float4 b0 = *(const float4*)&sB[k][c0];
            const float4 b1 = *(const float4*)&sB[k][c0 + 4];
            const float av[4] = {a.x, a.y, a.z, a.w};
            const float bv[8] = {b0.x, b0.y, b0.z, b0.w, b1.x, b1.y, b1.z, b1.w};
            #pragma unroll
            for (int i = 0; i < 4; i++)
                #pragma unroll
                for (int j = 0; j < 8; j++)
                    acc[i][j] = fmaf(av[i], bv[j], acc[i][j]);
        }
        __syncthreads();
    }

    // y = silu(acc + b1) -> sY (row-major [edge][feat])
    #pragma unroll
    for (int i = 0; i < 4; i++) {
        float t[8];
        #pragma unroll
        for (int j = 0; j < 8; j++) t[j] = silu_f(acc[i][j] + bias1[j]);
        *(float4*)&sY[r0 + i][c0]     = make_float4(t[0], t[1], t[2], t[3]);
        *(float4*)&sY[r0 + i][c0 + 4] = make_float4(t[4], t[5], t[6], t[7]);
    }

    float acc2[4][8];
    #pragma unroll
    for (int i = 0; i < 4; i++)
        #pragma unroll
        for (int j = 0; j < 8; j++) acc2[i][j] = 0.0f;

    __syncthreads();

    // ---- MLP2: [64 x 128] @ [128 x 128] ----
    for (int kk = 0; kk < H / BK; kk++) {
        const int k0 = kk * BK;
        {
            const float4* g = (const float4*)&eW2[(k0 + ty) * H + c0];
            *(float4*)&sB[ty][c0]     = g[0];
            *(float4*)&sB[ty][c0 + 4] = g[1];
        }
        __syncthreads();
        #pragma unroll
        for (int k = 0; k < BK; k++) {
            const int kg = k0 + k;
            const float4 b0 = *(const float4*)&sB[k][c0];
            const float4 b1 = *(const float4*)&sB[k][c0 + 4];
            const float bv[8] = {b0.x, b0.y, b0.z, b0.w, b1.x, b1.y, b1.z, b1.w};
            const float av[4] = { sY[r0 + 0][kg], sY[r0 + 1][kg],
                                  sY[r0 + 2][kg], sY[r0 + 3][kg] };
            #pragma unroll
            for (int i = 0; i < 4; i++)
                #pragma unroll
                for (int j = 0; j < 8; j++)
                    acc2[i][j] = fmaf(av[i], bv[j], acc2[i][j]);
        }
        __syncthreads();
    }

    // message = silu(acc2 + b2); scatter-add into agg[dst]
    #pragma unroll
    for (int i = 0; i < 4; i++) {
        const int e = e0 + r0 + i;
        if (e < E) {
            const int d = sDst[r0 + i];
            float* dst = &agg[d * H + c0];
            #pragma unroll
            for (int j = 0; j < 8; j++)
                atomic_add_f32(&dst[j], silu_f(acc2[i][j] + bias2[j]));
        }
    }
}

// ---------------------------------------------------------------------------
// Node kernel: node_input = [h | agg | role_e | color_e] (272), MLP1+silu,
// MLP2 (no silu), residual, LayerNorm, write out.
// ---------------------------------------------------------------------------
__global__ void __launch_bounds__(NT)
node_mlp_ln(const float* __restrict__ h,
            const float* __restrict__ agg,
            const int* __restrict__ ncol,
            const int* __restrict__ nrole,
            const float* __restrict__ role_emb,
            const float* __restrict__ col_emb,
            const float* __restrict__ nW1,
            const float* __restrict__ nb1,
            const float* __restrict__ nW2,
            const float* __restrict__ nb2,
            const float* __restrict__ ln_g,
            const float* __restrict__ ln_b,
            float* __restrict__ out,
            int N)
{
    __shared__ float sA[BK][BM + 4];
    __shared__ float sB[BK][H + 4];
    __shared__ float sY[BM][H + 4];
    __shared__ int sRole[BM], sCol[BM];
    __shared__ float sRoleE[48], sColE[24];

    const int tid = threadIdx.x;
    const int tx = tid & 15;
    const int ty = tid >> 4;
    const int r0 = ty * 4;
    const int c0 = tx * 8;
    const int n0 = blockIdx.x * BM;

    if (tid < 48) sRoleE[tid] = role_emb[tid];
    if (tid < 24) sColE[tid] = col_emb[tid];
    if (tid < BM) {
        int n = n0 + tid; if (n >= N) n = N - 1;
        sRole[tid] = nrole[n];
        sCol[tid]  = ncol[n];
    }

    float bias1[8], bias2[8], lg[8], lb[8];
    #pragma unroll
    for (int j = 0; j < 8; j++) {
        bias1[j] = nb1[c0 + j];
        bias2[j] = nb2[c0 + j];
        lg[j]    = ln_g[c0 + j];
        lb[j]    = ln_b[c0 + j];
    }

    float acc[4][8];
    #pragma unroll
    for (int i = 0; i < 4; i++)
        #pragma unroll
        for (int j = 0; j < 8; j++) acc[i][j] = 0.0f;

    __syncthreads();

    // ---- MLP1: [64 x 272] @ [272 x 128] ----
    for (int kk = 0; kk < NIN / BK; kk++) {
        const int k0 = kk * BK;
        {
            const int k = k0 + tx;
            #pragma unroll
            for (int it = 0; it < 4; it++) {
                const int r = ty + it * 16;
                int n = n0 + r; if (n >= N) n = N - 1;
                float v;
                if (k < 128) {
                    v = h[n * H + k];
                } else if (k < 256) {
                    v = agg[n * H + (k - 128)];
                } else {
                    const int j = k - 256;
                    v = (j < 8) ? sRoleE[sRole[r] * 8 + j]
                                : sColE[sCol[r] * 8 + (j - 8)];
                }
                sA[tx][r] = v;
            }
        }
        {
            const float4* g = (const float4*)&nW1[(k0 + ty) * H + c0];
            *(float4*)&sB[ty][c0]     = g[0];
            *(float4*)&sB[ty][c0 + 4] = g[1];
        }
        __syncthreads();
        #pragma unroll
        for (int k = 0; k < BK; k++) {
            const float4 a  = *(const float4*)&sA[k][r0];
            const float4 b0 = *(const float4*)&sB[k][c0];
            const float4 b1 = *(const float4*)&sB[k][c0 + 4];
            const float av[4] = {a.x, a.y, a.z, a.w};
            const float bv[8] = {b0.x, b0.y, b0.z, b0.w, b1.x, b1.y, b1.z, b1.w};
            #pragma unroll
            for (int i = 0; i < 4; i++)
                #pragma unroll
                for (int j = 0; j < 8; j++)
                    acc[i][j] = fmaf(av[i], bv[j], acc[i][j]);
        }
        __syncthreads();
    }

    #pragma unroll
    for (int i = 0; i < 4; i++) {
        float t[8];
        #pragma unroll
        for (int j = 0; j < 8; j++) t[j] = silu_f(acc[i][j] + bias1[j]);
        *(float4*)&sY[r0 + i][c0]     = make_float4(t[0], t[1], t[2], t[3]);
        *(float4*)&sY[r0 + i][c0 + 4] = make_float4(t[4], t[5], t[6], t[7]);
    }

    float acc2[4][8];
    #pragma unroll
    for (int i = 0; i < 4; i++)
        #pragma unroll
        for (int j = 0; j < 8; j++) acc2[i][j] = 0.0f;

    __syncthreads();

    // ---- MLP2: [64 x 128] @ [128 x 128] (no final silu) ----
    for (int kk = 0; kk < H / BK; kk++) {
        const int k0 = kk * BK;
        {
            const float4* g = (const float4*)&nW2[(k0 + ty) * H + c0];
            *(float4*)&sB[ty][c0]     = g[0];
            *(float4*)&sB[ty][c0 + 4] = g[1];
        }
        __syncthreads();
        #pragma unroll
        for (int k = 0; k < BK; k++) {
            const int kg = k0 + k;
            const float4 b0 = *(const float4*)&sB[k][c0];
            const float4 b1 = *(const float4*)&sB[k][c0 + 4];
            const float bv[8] = {b0.x, b0.y, b0.z, b0.w, b1.x, b1.y, b1.z, b1.w};
            const float av[4] = { sY[r0 + 0][kg], sY[r0 + 1][kg],
                                  sY[r0 + 2][kg], sY[r0 + 3][kg] };
            #pragma unroll
            for (int i = 0; i < 4; i++)
                #pragma unroll
                for (int j = 0; j < 8; j++)
                    acc2[i][j] = fmaf(av[i], bv[j], acc2[i][j]);
        }
        __syncthreads();
    }

    // residual + LayerNorm
    #pragma unroll
    for (int i = 0; i < 4; i++) {
        const int n = n0 + r0 + i;
        const int nc = (n < N) ? n : (N - 1);
        const float4 h0 = *(const float4*)&h[nc * H + c0];
        const float4 h1 = *(const float4*)&h[nc * H + c0 + 4];
        const float hv[8] = {h0.x, h0.y, h0.z, h0.w, h1.x, h1.y, h1.z, h1.w};
        float x[8];
        float s = 0.0f;
        #pragma unroll
        for (int j = 0; j < 8; j++) {
            x[j] = hv[j] + acc2[i][j] + bias2[j];
            s += x[j];
        }
        s += __shfl_xor(s, 1);
        s += __shfl_xor(s, 2);
        s += __shfl_xor(s, 4);
        s += __shfl_xor(s, 8);
        const float mu = s * (1.0f / 128.0f);
        float vs = 0.0f;
        #pragma unroll
        for (int j = 0; j < 8; j++) {
            const float dx = x[j] - mu;
            vs += dx * dx;
        }
        vs += __shfl_xor(vs, 1);
        vs += __shfl_xor(vs, 2);
        vs += __shfl_xor(vs, 4);
        vs += __shfl_xor(vs, 8);
        const float rstd = rsqrtf(vs * (1.0f / 128.0f) + LN_EPS);
        if (n < N) {
            float o[8];
            #pragma unroll
            for (int j = 0; j < 8; j++)
                o[j] = (x[j] - mu) * rstd * lg[j] + lb[j];
            *(float4*)&out[n * H + c0]     = make_float4(o[0], o[1], o[2], o[3]);
            *(float4*)&out[n * H + c0 + 4] = make_float4(o[4], o[5], o[6], o[7]);
        }
    }
}

extern "C" void kernel_launch(void* const* d_in, const int* in_sizes, int n_in,
                              void* d_out, int out_size, void* d_ws, size_t ws_size,
                              hipStream_t stream)
{
    const float* h        = (const float*)d_in[0];
    const int*   eidx     = (const int*)d_in[1];
    const int*   erel     = (const int*)d_in[2];
    const int*   ncol     = (const int*)d_in[3];
    const int*   nrole    = (const int*)d_in[4];
    const float* rel_emb  = (const float*)d_in[5];
    const float* role_emb = (const float*)d_in[6];
    const float* col_emb  = (const float*)d_in[7];
    const float* eW1      = (const float*)d_in[8];
    const float* eb1      = (const float*)d_in[9];
    const float* eW2      = (const float*)d_in[10];
    const float* eb2      = (const float*)d_in[11];
    const float* nW1      = (const float*)d_in[12];
    const float* nb1      = (const float*)d_in[13];
    const float* nW2      = (const float*)d_in[14];
    const float* nb2      = (const float*)d_in[15];
    const float* ln_g     = (const float*)d_in[16];
    const float* ln_b     = (const float*)d_in[17];

    const int N = in_sizes[0] / H;
    const int E = in_sizes[2];
    const int* esrc = eidx;
    const int* edst = eidx + E;

    float* agg = (float*)d_ws;   // N*H floats of scratch
    hipMemsetAsync(agg, 0, (size_t)N * H * sizeof(float), stream);

    dim3 blk(NT);
    edge_mlp_scatter<<<dim3((E + BM - 1) / BM), blk, 0, stream>>>(
        h, esrc, edst, erel, ncol, nrole, rel_emb, role_emb, col_emb,
        eW1, eb1, eW2, eb2, agg, E);

    node_mlp_ln<<<dim3((N + BM - 1) / BM), blk, 0, stream>>>(
        h, agg, ncol, nrole, role_emb, col_emb,
        nW1, nb1, nW2, nb2, ln_g, ln_b, (float*)d_out, N);
}